// Round 1
// baseline (370.002 us; speedup 1.0000x reference)
//
#include <hip/hip_runtime.h>

typedef unsigned short ushort_t;
typedef unsigned int u32;
typedef unsigned long long u64;
typedef __attribute__((ext_vector_type(4))) float f32x4;
typedef __attribute__((ext_vector_type(8))) short s16x8;

#define LOG2E 1.44269504088896340736f

__device__ __forceinline__ ushort_t f2bf(float f) {
    u32 u = __float_as_uint(f);
    u32 r = u + 0x7fffu + ((u >> 16) & 1u);
    return (ushort_t)(r >> 16);
}
__device__ __forceinline__ float bf2f(ushort_t h) {
    return __uint_as_float(((u32)h) << 16);
}
// async global->LDS, 16B per lane. LDS dest must be wave-uniform base + lane*16.
__device__ __forceinline__ void cp16(const void* g, void* l) {
    __builtin_amdgcn_global_load_lds(
        (const __attribute__((address_space(1))) u32*)g,
        (__attribute__((address_space(3))) u32*)l, 16, 0, 0);
}

// ---------------- conversion kernels ----------------
__global__ void cvt_qkv(const float* __restrict__ a, const float* __restrict__ b,
                        const float* __restrict__ c, ushort_t* __restrict__ oa,
                        ushort_t* __restrict__ ob, ushort_t* __restrict__ oc) {
    const float* s = blockIdx.y == 0 ? a : (blockIdx.y == 1 ? b : c);
    ushort_t* o = blockIdx.y == 0 ? oa : (blockIdx.y == 1 ? ob : oc);
    int i = (blockIdx.x * 256 + threadIdx.x) * 4;
    float4 v = *(const float4*)(s + i);
    u64 pk = (u64)f2bf(v.x) | ((u64)f2bf(v.y) << 16) |
             ((u64)f2bf(v.z) << 32) | ((u64)f2bf(v.w) << 48);
    *(u64*)(o + i) = pk;
}

__global__ void cvt_w(const float* __restrict__ a, const float* __restrict__ b,
                      const float* __restrict__ c, const float* __restrict__ d,
                      ushort_t* __restrict__ oa, ushort_t* __restrict__ ob,
                      ushort_t* __restrict__ oc, ushort_t* __restrict__ od) {
    const float* s; ushort_t* o;
    switch (blockIdx.y) {
        case 0: s = a; o = oa; break;
        case 1: s = b; o = ob; break;
        case 2: s = c; o = oc; break;
        default: s = d; o = od; break;
    }
    int i = (blockIdx.x * 256 + threadIdx.x) * 4;
    float4 v = *(const float4*)(s + i);
    u64 pk = (u64)f2bf(v.x) | ((u64)f2bf(v.y) << 16) |
             ((u64)f2bf(v.z) << 32) | ((u64)f2bf(v.w) << 48);
    *(u64*)(o + i) = pk;
}

__global__ void cvt_mask(const int* __restrict__ m, ushort_t* __restrict__ o) {
    int i = (blockIdx.x * 256 + threadIdx.x) * 4;
    int4 v = *(const int4*)(m + i);
    const ushort_t nb = 0xC6EA;  // bf16(-29952): additive mask bias
    u64 pk = (u64)(v.x ? 0 : nb) | ((u64)(v.y ? 0 : nb) << 16) |
             ((u64)(v.z ? 0 : nb) << 32) | ((u64)(v.w ? 0 : nb) << 48);
    *(u64*)(o + i) = pk;
}

// ---------------- NT GEMM: C[M=8192,N=512] = A[M,K=512] @ Bw[N,K]^T + bias ----------------
// MODE 0: store bf16 as q/k layout [B,H,S,64]
// MODE 1: store bf16 as vT layout [B,H,64,S]
// MODE 2: store fp32 row-major [M,512]
template <int MODE>
__global__ __launch_bounds__(256)
void gemm_nt(const ushort_t* __restrict__ A, const ushort_t* __restrict__ Bw,
             const float* __restrict__ bias, void* __restrict__ out) {
    constexpr int K = 512;
    __shared__ ushort_t As[128 * 32];
    __shared__ ushort_t Bs[128 * 32];
    const int tid = threadIdx.x;
    const int bm = blockIdx.x, bn = blockIdx.y;
    const int wave = tid >> 6, lane = tid & 63, quad = lane >> 4, l16 = lane & 15;
    const int wm = (wave >> 1) * 64, wn = (wave & 1) * 64;

    const ushort_t* Ag = A + (size_t)(bm * 128 + (tid >> 2)) * K + (tid & 3) * 8;
    const ushort_t* Bg = Bw + (size_t)(bn * 128 + (tid >> 2)) * K + (tid & 3) * 8;

    f32x4 acc[4][4];
#pragma unroll
    for (int i = 0; i < 4; i++)
#pragma unroll
        for (int j = 0; j < 4; j++) acc[i][j] = (f32x4){0.f, 0.f, 0.f, 0.f};

    for (int kt = 0; kt < K; kt += 32) {
        __syncthreads();
        cp16(Ag + kt, (char*)As + tid * 16);
        cp16(Ag + 64 * K + kt, (char*)As + 4096 + tid * 16);
        cp16(Bg + kt, (char*)Bs + tid * 16);
        cp16(Bg + 64 * K + kt, (char*)Bs + 4096 + tid * 16);
        __syncthreads();
        s16x8 af[4], bf[4];
#pragma unroll
        for (int i = 0; i < 4; i++)
            af[i] = *(const s16x8*)&As[(wm + i * 16 + l16) * 32 + quad * 8];
#pragma unroll
        for (int j = 0; j < 4; j++)
            bf[j] = *(const s16x8*)&Bs[(wn + j * 16 + l16) * 32 + quad * 8];
#pragma unroll
        for (int i = 0; i < 4; i++)
#pragma unroll
            for (int j = 0; j < 4; j++)
                acc[i][j] = __builtin_amdgcn_mfma_f32_16x16x32_bf16(af[i], bf[j], acc[i][j], 0, 0, 0);
    }

#pragma unroll
    for (int j = 0; j < 4; j++) {
        const int gn = bn * 128 + wn + j * 16 + l16;
        const float bv = bias[gn];
#pragma unroll
        for (int i = 0; i < 4; i++) {
#pragma unroll
            for (int p = 0; p < 4; p++) {
                const int gm = bm * 128 + wm + i * 16 + quad * 4 + p;
                const float val = acc[i][j][p] + bv;
                if (MODE == 2) {
                    ((float*)out)[(size_t)gm * 512 + gn] = val;
                } else {
                    const int b = gm >> 11, s = gm & 2047;
                    const int h = gn >> 6, d = gn & 63;
                    if (MODE == 0)
                        ((ushort_t*)out)[(((size_t)(b * 8 + h)) * 2048 + s) * 64 + d] = f2bf(val);
                    else
                        ((ushort_t*)out)[(((size_t)(b * 8 + h)) * 64 + d) * 2048 + s] = f2bf(val);
                }
            }
        }
    }
}

// ---------------- fused masked-softmax attention (flash-style) ----------------
// grid (S/128, H, B), 256 threads. q,k: [B,H,S,64] bf16. vT: [B,H,64,S] bf16.
// mb: [B,S,S] bf16 additive bias. x out: [B,S,512] bf16.
__global__ __launch_bounds__(256, 2)
void attn(const ushort_t* __restrict__ q, const ushort_t* __restrict__ k,
          const ushort_t* __restrict__ vT, const ushort_t* __restrict__ mb,
          ushort_t* __restrict__ x) {
    __shared__ ushort_t Qs[2][128 * 32];  // K-chain planes, 64B rows
    __shared__ ushort_t Ks[2][64 * 32];
    __shared__ ushort_t Vs[2][64 * 32];
    __shared__ ushort_t Ms[128 * 64];
    __shared__ ushort_t Ps[4][32 * 72];  // +8 pad breaks 128B-row bank aliasing

    const int tid = threadIdx.x;
    const int qt = blockIdx.x, h = blockIdx.y, b = blockIdx.z;
    const int wave = tid >> 6, lane = tid & 63, quad = lane >> 4, l16 = lane & 15;
    const size_t bh = (size_t)b * 8 + h;
    const ushort_t* qg = q + (bh * 2048 + qt * 128) * 64;
    const ushort_t* kg = k + bh * 2048 * 64;
    const ushort_t* vg = vT + bh * 64 * 2048;
    const ushort_t* mg = mb + ((size_t)b * 2048 + qt * 128) * 2048;

    {
        const int r = tid >> 2, c = (tid & 3) * 8;
#pragma unroll
        for (int rd = 0; rd < 4; rd++) {
            const int plane = rd >> 1, rb = (rd & 1) * 64;
            cp16(qg + (size_t)(rb + r) * 64 + plane * 32 + c,
                 (char*)Qs[plane] + (rd & 1) * 4096 + tid * 16);
        }
    }
    __syncthreads();
    s16x8 qa[2][2];
#pragma unroll
    for (int i = 0; i < 2; i++)
#pragma unroll
        for (int c = 0; c < 2; c++)
            qa[i][c] = *(const s16x8*)&Qs[c][(wave * 32 + i * 16 + l16) * 32 + quad * 8];

    float mst[2][4], lst[2][4];
    f32x4 O[2][4];
#pragma unroll
    for (int i = 0; i < 2; i++) {
#pragma unroll
        for (int p = 0; p < 4; p++) { mst[i][p] = -1e30f; lst[i][p] = 0.f; }
#pragma unroll
        for (int jd = 0; jd < 4; jd++) O[i][jd] = (f32x4){0.f, 0.f, 0.f, 0.f};
    }

    for (int kt = 0; kt < 2048; kt += 64) {
        __syncthreads();
        {
            const int r = tid >> 2, c = (tid & 3) * 8;
            cp16(kg + (size_t)(kt + r) * 64 + c, (char*)Ks[0] + tid * 16);
            cp16(kg + (size_t)(kt + r) * 64 + 32 + c, (char*)Ks[1] + tid * 16);
            cp16(vg + (size_t)r * 2048 + kt + c, (char*)Vs[0] + tid * 16);
            cp16(vg + (size_t)r * 2048 + kt + 32 + c, (char*)Vs[1] + tid * 16);
            const int r8 = tid >> 3, c8 = (tid & 7) * 8;
#pragma unroll
            for (int rd = 0; rd < 4; rd++)
                cp16(mg + (size_t)(r8 + rd * 32) * 2048 + kt + c8,
                     (char*)Ms + rd * 4096 + tid * 16);
        }
        __syncthreads();

        // S = Q K^T (fp32 accum)
        f32x4 S[2][4];
        s16x8 kb0[4], kb1[4];
#pragma unroll
        for (int j = 0; j < 4; j++) {
            kb0[j] = *(const s16x8*)&Ks[0][(j * 16 + l16) * 32 + quad * 8];
            kb1[j] = *(const s16x8*)&Ks[1][(j * 16 + l16) * 32 + quad * 8];
        }
#pragma unroll
        for (int i = 0; i < 2; i++)
#pragma unroll
            for (int j = 0; j < 4; j++) {
                f32x4 z = (f32x4){0.f, 0.f, 0.f, 0.f};
                z = __builtin_amdgcn_mfma_f32_16x16x32_bf16(qa[i][0], kb0[j], z, 0, 0, 0);
                S[i][j] = __builtin_amdgcn_mfma_f32_16x16x32_bf16(qa[i][1], kb1[j], z, 0, 0, 0);
            }

        // scale + mask bias + online softmax
#pragma unroll
        for (int i = 0; i < 2; i++) {
            const int rowb = wave * 32 + i * 16 + quad * 4;
            float tm[4] = {-3.0e38f, -3.0e38f, -3.0e38f, -3.0e38f};
#pragma unroll
            for (int j = 0; j < 4; j++)
#pragma unroll
                for (int p = 0; p < 4; p++) {
                    float sv = S[i][j][p] * 0.125f + bf2f(Ms[(rowb + p) * 64 + j * 16 + l16]);
                    S[i][j][p] = sv;
                    tm[p] = fmaxf(tm[p], sv);
                }
#pragma unroll
            for (int d = 1; d < 16; d <<= 1)
#pragma unroll
                for (int p = 0; p < 4; p++)
                    tm[p] = fmaxf(tm[p], __shfl_xor(tm[p], d));
#pragma unroll
            for (int p = 0; p < 4; p++) {
                const float mo = mst[i][p];
                const float mn = fmaxf(mo, tm[p]);
                mst[i][p] = mn;
                const float al = exp2f((mo - mn) * LOG2E);
                float rs = 0.f;
#pragma unroll
                for (int j = 0; j < 4; j++) {
                    const float pv = exp2f((S[i][j][p] - mn) * LOG2E);
                    S[i][j][p] = pv;
                    rs += pv;
                }
#pragma unroll
                for (int d = 1; d < 16; d <<= 1) rs += __shfl_xor(rs, d);
                lst[i][p] = lst[i][p] * al + rs;
#pragma unroll
                for (int jd = 0; jd < 4; jd++) O[i][jd][p] *= al;
#pragma unroll
                for (int j = 0; j < 4; j++)
                    Ps[wave][(i * 16 + quad * 4 + p) * 72 + j * 16 + l16] = f2bf(S[i][j][p]);
            }
        }
        __asm__ volatile("s_waitcnt lgkmcnt(0)" ::: "memory");  // P LDS write->read, wave-local

        // O += P V  (P via LDS C->A layout round-trip)
        s16x8 vb0[4], vb1[4];
#pragma unroll
        for (int jd = 0; jd < 4; jd++) {
            vb0[jd] = *(const s16x8*)&Vs[0][(jd * 16 + l16) * 32 + quad * 8];
            vb1[jd] = *(const s16x8*)&Vs[1][(jd * 16 + l16) * 32 + quad * 8];
        }
#pragma unroll
        for (int i = 0; i < 2; i++) {
            const s16x8 pa0 = *(const s16x8*)&Ps[wave][(i * 16 + l16) * 72 + quad * 8];
            const s16x8 pa1 = *(const s16x8*)&Ps[wave][(i * 16 + l16) * 72 + 32 + quad * 8];
#pragma unroll
            for (int jd = 0; jd < 4; jd++) {
                O[i][jd] = __builtin_amdgcn_mfma_f32_16x16x32_bf16(pa0, vb0[jd], O[i][jd], 0, 0, 0);
                O[i][jd] = __builtin_amdgcn_mfma_f32_16x16x32_bf16(pa1, vb1[jd], O[i][jd], 0, 0, 0);
            }
        }
    }

#pragma unroll
    for (int i = 0; i < 2; i++) {
        float rl[4];
#pragma unroll
        for (int p = 0; p < 4; p++) rl[p] = 1.0f / lst[i][p];
#pragma unroll
        for (int jd = 0; jd < 4; jd++)
#pragma unroll
            for (int p = 0; p < 4; p++) {
                const int srow = qt * 128 + wave * 32 + i * 16 + quad * 4 + p;
                x[((size_t)b * 2048 + srow) * 512 + h * 64 + jd * 16 + l16] =
                    f2bf(O[i][jd][p] * rl[p]);
            }
    }
}

// ---------------- launch ----------------
extern "C" void kernel_launch(void* const* d_in, const int* in_sizes, int n_in,
                              void* d_out, int out_size, void* d_ws, size_t ws_size,
                              hipStream_t stream) {
    const float* query = (const float*)d_in[0];
    const float* key_ = (const float*)d_in[1];
    const float* value = (const float*)d_in[2];
    const int* mask = (const int*)d_in[3];
    const float* Wq = (const float*)d_in[4];
    const float* bq = (const float*)d_in[5];
    const float* Wk = (const float*)d_in[6];
    const float* bk = (const float*)d_in[7];
    const float* Wv = (const float*)d_in[8];
    const float* bv = (const float*)d_in[9];
    const float* Wo = (const float*)d_in[10];
    const float* bo = (const float*)d_in[11];

    const size_t E = 4194304;  // 8192*512
    const size_t W = 262144;   // 512*512
    ushort_t* qb = (ushort_t*)d_ws;
    ushort_t* kb = qb + E;
    ushort_t* vb = kb + E;
    ushort_t* Wqb = vb + E;
    ushort_t* Wkb = Wqb + W;
    ushort_t* Wvb = Wkb + W;
    ushort_t* Wob = Wvb + W;
    ushort_t* maskb = Wob + W;
    ushort_t* qp = maskb + (size_t)4 * 2048 * 2048;
    ushort_t* kp = qp + E;
    ushort_t* vTp = kp + E;
    ushort_t* xp = vTp + E;

    cvt_qkv<<<dim3(4096, 3), 256, 0, stream>>>(query, key_, value, qb, kb, vb);
    cvt_w<<<dim3(256, 4), 256, 0, stream>>>(Wq, Wk, Wv, Wo, Wqb, Wkb, Wvb, Wob);
    cvt_mask<<<dim3(16384), 256, 0, stream>>>(mask, maskb);

    dim3 gg(64, 4);
    gemm_nt<0><<<gg, 256, 0, stream>>>(qb, Wqb, bq, qp);
    gemm_nt<0><<<gg, 256, 0, stream>>>(kb, Wkb, bk, kp);
    gemm_nt<1><<<gg, 256, 0, stream>>>(vb, Wvb, bv, vTp);

    attn<<<dim3(16, 8, 4), 256, 0, stream>>>(qp, kp, vTp, maskb, xp);

    gemm_nt<2><<<gg, 256, 0, stream>>>(xp, Wob, bo, d_out);
}

// Round 2
// 303.053 us; speedup vs baseline: 1.2209x; 1.2209x over previous
//
#include <hip/hip_runtime.h>

typedef unsigned short ushort_t;
typedef unsigned int u32;
typedef unsigned long long u64;
typedef __attribute__((ext_vector_type(4))) float f32x4;
typedef __attribute__((ext_vector_type(8))) short s16x8;

#define LOG2E 1.44269504088896340736f

__device__ __forceinline__ ushort_t f2bf(float f) {
    u32 u = __float_as_uint(f);
    u32 r = u + 0x7fffu + ((u >> 16) & 1u);
    return (ushort_t)(r >> 16);
}
__device__ __forceinline__ float bf2f(ushort_t h) {
    return __uint_as_float(((u32)h) << 16);
}
// async global->LDS, 16B per lane. LDS dest must be wave-uniform base + lane*16 (contiguous).
__device__ __forceinline__ void cp16(const void* g, void* l) {
    __builtin_amdgcn_global_load_lds(
        (const __attribute__((address_space(1))) u32*)g,
        (__attribute__((address_space(3))) u32*)l, 16, 0, 0);
}

// ---------------- fp32 -> bf16 conversion ----------------
__global__ void cvt_qkv(const float* __restrict__ a, const float* __restrict__ b,
                        const float* __restrict__ c, ushort_t* __restrict__ oa,
                        ushort_t* __restrict__ ob, ushort_t* __restrict__ oc) {
    const float* s = blockIdx.y == 0 ? a : (blockIdx.y == 1 ? b : c);
    ushort_t* o = blockIdx.y == 0 ? oa : (blockIdx.y == 1 ? ob : oc);
    int i = (blockIdx.x * 256 + threadIdx.x) * 4;
    float4 v = *(const float4*)(s + i);
    u64 pk = (u64)f2bf(v.x) | ((u64)f2bf(v.y) << 16) |
             ((u64)f2bf(v.z) << 32) | ((u64)f2bf(v.w) << 48);
    *(u64*)(o + i) = pk;
}

__global__ void cvt_w(const float* __restrict__ a, const float* __restrict__ b,
                      const float* __restrict__ c, const float* __restrict__ d,
                      ushort_t* __restrict__ oa, ushort_t* __restrict__ ob,
                      ushort_t* __restrict__ oc, ushort_t* __restrict__ od) {
    const float* s; ushort_t* o;
    switch (blockIdx.y) {
        case 0: s = a; o = oa; break;
        case 1: s = b; o = ob; break;
        case 2: s = c; o = oc; break;
        default: s = d; o = od; break;
    }
    int i = (blockIdx.x * 256 + threadIdx.x) * 4;
    float4 v = *(const float4*)(s + i);
    u64 pk = (u64)f2bf(v.x) | ((u64)f2bf(v.y) << 16) |
             ((u64)f2bf(v.z) << 32) | ((u64)f2bf(v.w) << 48);
    *(u64*)(o + i) = pk;
}

// ---------------- mask -> per-lane fragment-ordered bf16 bias ----------------
// out chunk per (b, kt64, qgroup16): 1024 ushorts; lane reads 16 contiguous us:
// us[mt*4+p] = bias(mask[q = qg*16 + l16][k = kt*64 + mt*16 + quad*4 + p])
__global__ __launch_bounds__(256) void prep_mask(const int* __restrict__ m,
                                                 ushort_t* __restrict__ mf) {
    __shared__ ushort_t ms[64 * 72];  // [qrow][k], +8 pad
    const int tid = threadIdx.x;
    const int kt = blockIdx.x, qq = blockIdx.y, b = blockIdx.z;
    const int* mg = m + ((size_t)(b * 2048 + qq * 64)) * 2048 + kt * 64;
#pragma unroll
    for (int i = 0; i < 4; i++) {
        int idx = tid + i * 256;
        int row = idx >> 4, c4 = (idx & 15) * 4;
        int4 v = *(const int4*)(mg + (size_t)row * 2048 + c4);
        u32 d0 = (v.x ? 0u : 0xC6EAu) | ((v.y ? 0u : 0xC6EAu) << 16);
        u32 d1 = (v.z ? 0u : 0xC6EAu) | ((v.w ? 0u : 0xC6EAu) << 16);
        *(uint2*)&ms[row * 72 + c4] = make_uint2(d0, d1);
    }
    __syncthreads();
    const int w = tid >> 6, lane = tid & 63, quad = (lane >> 4), l16 = lane & 15;
    u32 dw[8];
#pragma unroll
    for (int mt = 0; mt < 4; mt++) {
        uint2 t = *(const uint2*)&ms[(w * 16 + l16) * 72 + mt * 16 + quad * 4];
        dw[mt * 2] = t.x;
        dw[mt * 2 + 1] = t.y;
    }
    ushort_t* out = mf + ((((size_t)b * 32 + kt) * 128) + qq * 4 + w) * 1024 + lane * 16;
    *(uint4*)out = make_uint4(dw[0], dw[1], dw[2], dw[3]);
    *(uint4*)(out + 8) = make_uint4(dw[4], dw[5], dw[6], dw[7]);
}

// ---------------- fused q/k/v projection: 128x64 tile NT GEMM ----------------
// z=0: q (scaled 1/8, [B,H,S,64]); z=1: k ([B,H,S,64]); z=2: v (vT [B,H,64,S])
__global__ __launch_bounds__(256)
void gemm_qkv(const ushort_t* __restrict__ Aq, const ushort_t* __restrict__ Ak,
              const ushort_t* __restrict__ Av, const ushort_t* __restrict__ Wq,
              const ushort_t* __restrict__ Wk, const ushort_t* __restrict__ Wv,
              const float* __restrict__ bq, const float* __restrict__ bk,
              const float* __restrict__ bv, ushort_t* __restrict__ oq,
              ushort_t* __restrict__ ok, ushort_t* __restrict__ ov) {
    const int z = blockIdx.z;
    const ushort_t* A = z == 0 ? Aq : (z == 1 ? Ak : Av);
    const ushort_t* W = z == 0 ? Wq : (z == 1 ? Wk : Wv);
    const float* bias = z == 0 ? bq : (z == 1 ? bk : bv);
    ushort_t* out = z == 0 ? oq : (z == 1 ? ok : ov);
    const float scale = z == 0 ? 0.125f : 1.0f;

    __shared__ ushort_t As[128 * 32];
    __shared__ ushort_t Bs[64 * 32];
    const int tid = threadIdx.x, bm = blockIdx.x, bn = blockIdx.y;
    const int wave = tid >> 6, lane = tid & 63, quad = lane >> 4, l16 = lane & 15;
    const ushort_t* Ag = A + (size_t)(bm * 128 + (tid >> 2)) * 512 + (tid & 3) * 8;
    const ushort_t* Bg = W + (size_t)(bn * 64 + (tid >> 2)) * 512 + (tid & 3) * 8;

    f32x4 acc[2][4];
#pragma unroll
    for (int i = 0; i < 2; i++)
#pragma unroll
        for (int j = 0; j < 4; j++) acc[i][j] = (f32x4){0.f, 0.f, 0.f, 0.f};

    for (int kt = 0; kt < 512; kt += 32) {
        __syncthreads();
        cp16(Ag + kt, (char*)As + tid * 16);
        cp16(Ag + 64 * 512 + kt, (char*)As + 4096 + tid * 16);
        cp16(Bg + kt, (char*)Bs + tid * 16);
        __syncthreads();
        s16x8 af[2], bf[4];
#pragma unroll
        for (int i = 0; i < 2; i++)
            af[i] = *(const s16x8*)&As[(wave * 32 + i * 16 + l16) * 32 + quad * 8];
#pragma unroll
        for (int j = 0; j < 4; j++)
            bf[j] = *(const s16x8*)&Bs[(j * 16 + l16) * 32 + quad * 8];
#pragma unroll
        for (int i = 0; i < 2; i++)
#pragma unroll
            for (int j = 0; j < 4; j++)
                acc[i][j] = __builtin_amdgcn_mfma_f32_16x16x32_bf16(af[i], bf[j], acc[i][j], 0, 0, 0);
    }

#pragma unroll
    for (int j = 0; j < 4; j++) {
        const int gn = bn * 64 + j * 16 + l16;
        const float bb = bias[gn];
        const int hh = gn >> 6, dd = gn & 63;
#pragma unroll
        for (int i = 0; i < 2; i++) {
            const int gm0 = bm * 128 + wave * 32 + i * 16 + quad * 4;
            const int bi = gm0 >> 11, s0 = gm0 & 2047;
            if (z == 2) {
                u32 lo = (u32)f2bf(acc[i][j][0] + bb) | ((u32)f2bf(acc[i][j][1] + bb) << 16);
                u32 hi = (u32)f2bf(acc[i][j][2] + bb) | ((u32)f2bf(acc[i][j][3] + bb) << 16);
                *(uint2*)&out[(((size_t)(bi * 8 + hh)) * 64 + dd) * 2048 + s0] = make_uint2(lo, hi);
            } else {
#pragma unroll
                for (int p = 0; p < 4; p++)
                    out[(((size_t)(bi * 8 + hh)) * 2048 + s0 + p) * 64 + dd] =
                        f2bf((acc[i][j][p] + bb) * scale);
            }
        }
    }
}

// ---------------- output projection: 128x64 tile, fp32 out ----------------
__global__ __launch_bounds__(256)
void gemm_out(const ushort_t* __restrict__ A, const ushort_t* __restrict__ W,
              const float* __restrict__ bias, float* __restrict__ out) {
    __shared__ ushort_t As[128 * 32];
    __shared__ ushort_t Bs[64 * 32];
    const int tid = threadIdx.x, bm = blockIdx.x, bn = blockIdx.y;
    const int wave = tid >> 6, lane = tid & 63, quad = lane >> 4, l16 = lane & 15;
    const ushort_t* Ag = A + (size_t)(bm * 128 + (tid >> 2)) * 512 + (tid & 3) * 8;
    const ushort_t* Bg = W + (size_t)(bn * 64 + (tid >> 2)) * 512 + (tid & 3) * 8;

    f32x4 acc[2][4];
#pragma unroll
    for (int i = 0; i < 2; i++)
#pragma unroll
        for (int j = 0; j < 4; j++) acc[i][j] = (f32x4){0.f, 0.f, 0.f, 0.f};

    for (int kt = 0; kt < 512; kt += 32) {
        __syncthreads();
        cp16(Ag + kt, (char*)As + tid * 16);
        cp16(Ag + 64 * 512 + kt, (char*)As + 4096 + tid * 16);
        cp16(Bg + kt, (char*)Bs + tid * 16);
        __syncthreads();
        s16x8 af[2], bf[4];
#pragma unroll
        for (int i = 0; i < 2; i++)
            af[i] = *(const s16x8*)&As[(wave * 32 + i * 16 + l16) * 32 + quad * 8];
#pragma unroll
        for (int j = 0; j < 4; j++)
            bf[j] = *(const s16x8*)&Bs[(j * 16 + l16) * 32 + quad * 8];
#pragma unroll
        for (int i = 0; i < 2; i++)
#pragma unroll
            for (int j = 0; j < 4; j++)
                acc[i][j] = __builtin_amdgcn_mfma_f32_16x16x32_bf16(af[i], bf[j], acc[i][j], 0, 0, 0);
    }

#pragma unroll
    for (int j = 0; j < 4; j++) {
        const int gn = bn * 64 + j * 16 + l16;
        const float bb = bias[gn];
#pragma unroll
        for (int i = 0; i < 2; i++) {
            const int gm0 = bm * 128 + wave * 32 + i * 16 + quad * 4;
#pragma unroll
            for (int p = 0; p < 4; p++)
                out[(size_t)(gm0 + p) * 512 + gn] = acc[i][j][p] + bb;
        }
    }
}

// ---------------- fused attention: S^T formulation ----------------
// grid (32 qtile, 8 h, 4 b), 256 thr. Each wave owns 16 q-rows (q = l16).
// S^T = K Q^T: C col=l16=q, row=quad*4+p=kpos -> softmax reduces in-lane + 2 shfl.
// O^T = V^T P^T: C col=l16=q matches m/l/alpha state lanes exactly.
__global__ __launch_bounds__(256, 4)
void attn(const ushort_t* __restrict__ q, const ushort_t* __restrict__ k,
          const ushort_t* __restrict__ vT, const ushort_t* __restrict__ mf,
          ushort_t* __restrict__ x) {
    __shared__ ushort_t Qs[2][64 * 32];  // plane = d-half, row=q, 64B rows
    __shared__ ushort_t Ks[2][64 * 32];  // plane = d-half, row=kpos
    __shared__ ushort_t Vs[2][64 * 32];  // plane = kpos-half, row=d (from vT)
    __shared__ ushort_t Ps[4 * 16 * 72]; // per-wave P[q=16][kpos=64], row 144B (bank-optimal)

    const int tid = threadIdx.x;
    const int qt = blockIdx.x, h = blockIdx.y, b = blockIdx.z;
    const int w = tid >> 6, lane = tid & 63, quad = lane >> 4, l16 = lane & 15;
    const size_t bh = (size_t)b * 8 + h;
    const ushort_t* qg = q + (bh * 2048 + qt * 64) * 64;
    const ushort_t* kg = k + bh * 2048 * 64;
    const ushort_t* vg = vT + bh * 64 * 2048;
    const ushort_t* mbase = mf + (((size_t)b * 32) * 128 + qt * 4 + w) * 1024 + lane * 16;
    const int r = tid >> 2, c = (tid & 3) * 8;

    cp16(qg + (size_t)r * 64 + c, (char*)Qs[0] + tid * 16);
    cp16(qg + (size_t)r * 64 + 32 + c, (char*)Qs[1] + tid * 16);
    __syncthreads();
    s16x8 qbf[2];
#pragma unroll
    for (int kk = 0; kk < 2; kk++)
        qbf[kk] = *(const s16x8*)&Qs[kk][(w * 16 + l16) * 32 + quad * 8];

    float mo = -3.0e38f, lsum = 0.f;
    f32x4 ot[4];
#pragma unroll
    for (int dt = 0; dt < 4; dt++) ot[dt] = (f32x4){0.f, 0.f, 0.f, 0.f};

    for (int kt = 0; kt < 2048; kt += 64) {
        const int it = kt >> 6;
        // mask fragment: 2 coalesced dwordx4, L2-hot (reused by 8 h-blocks)
        const ushort_t* mptr = mbase + (size_t)it * 131072;
        uint4 mv0 = *(const uint4*)mptr;
        uint4 mv1 = *(const uint4*)(mptr + 8);
        u32 mw[8] = {mv0.x, mv0.y, mv0.z, mv0.w, mv1.x, mv1.y, mv1.z, mv1.w};

        __syncthreads();
        cp16(kg + (size_t)(kt + r) * 64 + c, (char*)Ks[0] + tid * 16);
        cp16(kg + (size_t)(kt + r) * 64 + 32 + c, (char*)Ks[1] + tid * 16);
        cp16(vg + (size_t)r * 2048 + kt + c, (char*)Vs[0] + tid * 16);
        cp16(vg + (size_t)r * 2048 + kt + 32 + c, (char*)Vs[1] + tid * 16);
        __syncthreads();

        // S^T = K Q^T  (q pre-scaled by 1/8 in projection)
        f32x4 st[4];
#pragma unroll
        for (int mt = 0; mt < 4; mt++) {
            s16x8 ka0 = *(const s16x8*)&Ks[0][(mt * 16 + l16) * 32 + quad * 8];
            s16x8 ka1 = *(const s16x8*)&Ks[1][(mt * 16 + l16) * 32 + quad * 8];
            f32x4 z = (f32x4){0.f, 0.f, 0.f, 0.f};
            z = __builtin_amdgcn_mfma_f32_16x16x32_bf16(ka0, qbf[0], z, 0, 0, 0);
            st[mt] = __builtin_amdgcn_mfma_f32_16x16x32_bf16(ka1, qbf[1], st[mt] = z, 0, 0, 0);
        }

        // mask add + online softmax over k (in-lane 16 + 2 shuffles)
        float tm = -3.0e38f;
#pragma unroll
        for (int mt = 0; mt < 4; mt++)
#pragma unroll
            for (int p = 0; p < 4; p++) {
                const int idx = mt * 4 + p;
                float sv = st[mt][p] + bf2f((ushort_t)((mw[idx >> 1] >> ((idx & 1) * 16)) & 0xffff));
                st[mt][p] = sv;
                tm = fmaxf(tm, sv);
            }
        tm = fmaxf(tm, __shfl_xor(tm, 16));
        tm = fmaxf(tm, __shfl_xor(tm, 32));
        const float mn = fmaxf(mo, tm);
        const float al = exp2f((mo - mn) * LOG2E);
        float rs = 0.f;
#pragma unroll
        for (int mt = 0; mt < 4; mt++)
#pragma unroll
            for (int p = 0; p < 4; p++) {
                const float pv = exp2f((st[mt][p] - mn) * LOG2E);
                st[mt][p] = pv;
                rs += pv;
            }
        rs += __shfl_xor(rs, 16);
        rs += __shfl_xor(rs, 32);
        lsum = lsum * al + rs;
        mo = mn;
#pragma unroll
        for (int dt = 0; dt < 4; dt++) ot[dt] *= al;

        // P -> LDS [q][kpos] (b64 writes, bank-optimal), then B-frag b128 reads
        const int pbase = w * 1152 + l16 * 72;
#pragma unroll
        for (int mt = 0; mt < 4; mt++) {
            u32 lo = (u32)f2bf(st[mt][0]) | ((u32)f2bf(st[mt][1]) << 16);
            u32 hi = (u32)f2bf(st[mt][2]) | ((u32)f2bf(st[mt][3]) << 16);
            *(uint2*)&Ps[pbase + mt * 16 + quad * 4] = make_uint2(lo, hi);
        }
        __asm__ volatile("s_waitcnt lgkmcnt(0)" ::: "memory");  // wave-local P write->read

        const s16x8 pb0 = *(const s16x8*)&Ps[pbase + quad * 8];
        const s16x8 pb1 = *(const s16x8*)&Ps[pbase + 32 + quad * 8];
#pragma unroll
        for (int dt = 0; dt < 4; dt++) {
            s16x8 va0 = *(const s16x8*)&Vs[0][(dt * 16 + l16) * 32 + quad * 8];
            s16x8 va1 = *(const s16x8*)&Vs[1][(dt * 16 + l16) * 32 + quad * 8];
            ot[dt] = __builtin_amdgcn_mfma_f32_16x16x32_bf16(va0, pb0, ot[dt], 0, 0, 0);
            ot[dt] = __builtin_amdgcn_mfma_f32_16x16x32_bf16(va1, pb1, ot[dt], 0, 0, 0);
        }
    }

    const float inv = 1.0f / lsum;
    const int qrow = qt * 64 + w * 16 + l16;
#pragma unroll
    for (int dt = 0; dt < 4; dt++) {
        u32 lo = (u32)f2bf(ot[dt][0] * inv) | ((u32)f2bf(ot[dt][1] * inv) << 16);
        u32 hi = (u32)f2bf(ot[dt][2] * inv) | ((u32)f2bf(ot[dt][3] * inv) << 16);
        *(uint2*)&x[((size_t)b * 2048 + qrow) * 512 + h * 64 + dt * 16 + quad * 4] =
            make_uint2(lo, hi);
    }
}

// ---------------- launch ----------------
extern "C" void kernel_launch(void* const* d_in, const int* in_sizes, int n_in,
                              void* d_out, int out_size, void* d_ws, size_t ws_size,
                              hipStream_t stream) {
    const float* query = (const float*)d_in[0];
    const float* key_ = (const float*)d_in[1];
    const float* value = (const float*)d_in[2];
    const int* mask = (const int*)d_in[3];
    const float* Wq = (const float*)d_in[4];
    const float* bq = (const float*)d_in[5];
    const float* Wk = (const float*)d_in[6];
    const float* bk = (const float*)d_in[7];
    const float* Wv = (const float*)d_in[8];
    const float* bv = (const float*)d_in[9];
    const float* Wo = (const float*)d_in[10];
    const float* bo = (const float*)d_in[11];

    const size_t E = 4194304;  // 8192*512
    const size_t W = 262144;   // 512*512
    ushort_t* qb = (ushort_t*)d_ws;
    ushort_t* kb = qb + E;
    ushort_t* vb = kb + E;
    ushort_t* Wqb = vb + E;
    ushort_t* Wkb = Wqb + W;
    ushort_t* Wvb = Wkb + W;
    ushort_t* Wob = Wvb + W;
    ushort_t* mfb = Wob + W;  // 4*32*128*1024 = 16.78M ushorts
    ushort_t* qp = mfb + (size_t)4 * 2048 * 2048;
    ushort_t* kp = qp + E;
    ushort_t* vTp = kp + E;
    ushort_t* xp = vTp + E;

    cvt_qkv<<<dim3(4096, 3), 256, 0, stream>>>(query, key_, value, qb, kb, vb);
    cvt_w<<<dim3(256, 4), 256, 0, stream>>>(Wq, Wk, Wv, Wo, Wqb, Wkb, Wvb, Wob);
    prep_mask<<<dim3(32, 32, 4), 256, 0, stream>>>(mask, mfb);

    gemm_qkv<<<dim3(64, 8, 3), 256, 0, stream>>>(qb, kb, vb, Wqb, Wkb, Wvb,
                                                 bq, bk, bv, qp, kp, vTp);

    attn<<<dim3(32, 8, 4), 256, 0, stream>>>(qp, kp, vTp, mfb, xp);

    gemm_out<<<dim3(64, 8), 256, 0, stream>>>(xp, Wob, bo, (float*)d_out);
}

// Round 3
// 296.807 us; speedup vs baseline: 1.2466x; 1.0210x over previous
//
#include <hip/hip_runtime.h>

typedef unsigned short ushort_t;
typedef unsigned int u32;
typedef unsigned long long u64;
typedef __attribute__((ext_vector_type(4))) float f32x4;
typedef __attribute__((ext_vector_type(16))) float f32x16;
typedef __attribute__((ext_vector_type(8))) short s16x8;

__device__ __forceinline__ ushort_t f2bf(float f) {
    u32 u = __float_as_uint(f);
    u32 r = u + 0x7fffu + ((u >> 16) & 1u);
    return (ushort_t)(r >> 16);
}
__device__ __forceinline__ u32 pk_trunc(float a, float b) {
    // truncating bf16 pair pack (P only; systematic -delta cancels in O/l)
    return (__float_as_uint(a) >> 16) | (__float_as_uint(b) & 0xffff0000u);
}
// async global->LDS, 16B/lane; LDS dest = wave-uniform base + lane*16.
__device__ __forceinline__ void cp16(const void* g, void* l) {
    __builtin_amdgcn_global_load_lds(
        (const __attribute__((address_space(1))) u32*)g,
        (__attribute__((address_space(3))) u32*)l, 16, 0, 0);
}

// ---------------- fp32 -> bf16 conversion ----------------
__global__ void cvt_qkv(const float* __restrict__ a, const float* __restrict__ b,
                        const float* __restrict__ c, ushort_t* __restrict__ oa,
                        ushort_t* __restrict__ ob, ushort_t* __restrict__ oc) {
    const float* s = blockIdx.y == 0 ? a : (blockIdx.y == 1 ? b : c);
    ushort_t* o = blockIdx.y == 0 ? oa : (blockIdx.y == 1 ? ob : oc);
    int i = (blockIdx.x * 256 + threadIdx.x) * 4;
    float4 v = *(const float4*)(s + i);
    u64 pk = (u64)f2bf(v.x) | ((u64)f2bf(v.y) << 16) |
             ((u64)f2bf(v.z) << 32) | ((u64)f2bf(v.w) << 48);
    *(u64*)(o + i) = pk;
}

__global__ void cvt_w(const float* __restrict__ a, const float* __restrict__ b,
                      const float* __restrict__ c, const float* __restrict__ d,
                      ushort_t* __restrict__ oa, ushort_t* __restrict__ ob,
                      ushort_t* __restrict__ oc, ushort_t* __restrict__ od) {
    const float* s; ushort_t* o;
    switch (blockIdx.y) {
        case 0: s = a; o = oa; break;
        case 1: s = b; o = ob; break;
        case 2: s = c; o = oc; break;
        default: s = d; o = od; break;
    }
    int i = (blockIdx.x * 256 + threadIdx.x) * 4;
    float4 v = *(const float4*)(s + i);
    u64 pk = (u64)f2bf(v.x) | ((u64)f2bf(v.y) << 16) |
             ((u64)f2bf(v.z) << 32) | ((u64)f2bf(v.w) << 48);
    *(u64*)(o + i) = pk;
}

// ---------------- mask -> per-lane 32x32-fragment-ordered bf16 bias ----------------
// chunk per (b,kt64,qt128,w): 1024 u32 laid out [j=0..3][lane=0..63][4 u32].
// u32 mi = mt*8+r4*2+bb for lane L covers q=qt*128+w*32+(L&31),
// kpos pair = kt*64 + mt*32 + r4*8 + (L>>5)*4 + bb*2 + {0,1}. masked -> bf16(-29952).
__global__ __launch_bounds__(256) void prep_mask(const int* __restrict__ m,
                                                 u32* __restrict__ mf) {
    __shared__ ushort_t ms[128 * 68];  // [q 128][k 64], +4 pad
    const int tid = threadIdx.x;
    const int kt = blockIdx.x, qt = blockIdx.y, b = blockIdx.z;
    const int* mg = m + ((size_t)(b * 2048 + qt * 128)) * 2048 + kt * 64;
#pragma unroll
    for (int rep = 0; rep < 8; rep++) {
        int linear = rep * 256 + tid;
        int row = linear >> 4, ci = linear & 15;
        int4 v = *(const int4*)(mg + (size_t)row * 2048 + ci * 4);
        u32 d0 = (v.x ? 0u : 0xC6EAu) | ((v.y ? 0u : 0xC6EAu) << 16);
        u32 d1 = (v.z ? 0u : 0xC6EAu) | ((v.w ? 0u : 0xC6EAu) << 16);
        *(uint2*)&ms[row * 68 + ci * 4] = make_uint2(d0, d1);
    }
    __syncthreads();
    const int w = tid >> 6, L = tid & 63, hf = L >> 5, q5 = L & 31;
    const int ql = w * 32 + q5;
    u32* out = mf + ((((size_t)b * 32 + kt) * 16 + qt) * 4 + w) * 1024 + L * 4;
    u32 vals[16];
#pragma unroll
    for (int mi = 0; mi < 16; mi++) {
        int mt = mi >> 3, r4 = (mi >> 1) & 3, bb = mi & 1;
        int kl = mt * 32 + r4 * 8 + hf * 4 + bb * 2;
        vals[mi] = *(const u32*)&ms[ql * 68 + kl];
    }
#pragma unroll
    for (int j = 0; j < 4; j++)
        *(uint4*)(out + j * 256) =
            make_uint4(vals[j * 4], vals[j * 4 + 1], vals[j * 4 + 2], vals[j * 4 + 3]);
}

// ---------------- fused q/k/v projection: 128x128 NT GEMM (m97 structure) ----------------
// z=0: q scaled by 0.125*log2(e), [B,H,S,64]; z=1: k [B,H,S,64]; z=2: vT [B,H,64,S]
__global__ __launch_bounds__(256)
void gemm_qkv(const ushort_t* __restrict__ Aq, const ushort_t* __restrict__ Ak,
              const ushort_t* __restrict__ Av, const ushort_t* __restrict__ Wq,
              const ushort_t* __restrict__ Wk, const ushort_t* __restrict__ Wv,
              const float* __restrict__ bq, const float* __restrict__ bk,
              const float* __restrict__ bv, ushort_t* __restrict__ oq,
              ushort_t* __restrict__ ok, ushort_t* __restrict__ ov) {
    constexpr int K = 512;
    const int z = blockIdx.z;
    const ushort_t* A = z == 0 ? Aq : (z == 1 ? Ak : Av);
    const ushort_t* Bw = z == 0 ? Wq : (z == 1 ? Wk : Wv);
    const float* bias = z == 0 ? bq : (z == 1 ? bk : bv);
    ushort_t* out = z == 0 ? oq : (z == 1 ? ok : ov);
    const float scale = z == 0 ? 0.18033688f : 1.0f;  // 0.125*log2(e)

    __shared__ ushort_t As[128 * 32];
    __shared__ ushort_t Bs[128 * 32];
    const int tid = threadIdx.x;
    const int bm = blockIdx.x, bn = blockIdx.y;
    const int wave = tid >> 6, lane = tid & 63, quad = lane >> 4, l16 = lane & 15;
    const int wm = (wave >> 1) * 64, wn = (wave & 1) * 64;

    const ushort_t* Ag = A + (size_t)(bm * 128 + (tid >> 2)) * K + (tid & 3) * 8;
    const ushort_t* Bg = Bw + (size_t)(bn * 128 + (tid >> 2)) * K + (tid & 3) * 8;

    f32x4 acc[4][4];
#pragma unroll
    for (int i = 0; i < 4; i++)
#pragma unroll
        for (int j = 0; j < 4; j++) acc[i][j] = (f32x4){0.f, 0.f, 0.f, 0.f};

    for (int kt = 0; kt < K; kt += 32) {
        __syncthreads();
        cp16(Ag + kt, (char*)As + tid * 16);
        cp16(Ag + 64 * K + kt, (char*)As + 4096 + tid * 16);
        cp16(Bg + kt, (char*)Bs + tid * 16);
        cp16(Bg + 64 * K + kt, (char*)Bs + 4096 + tid * 16);
        __syncthreads();
        s16x8 af[4], bf[4];
#pragma unroll
        for (int i = 0; i < 4; i++)
            af[i] = *(const s16x8*)&As[(wm + i * 16 + l16) * 32 + quad * 8];
#pragma unroll
        for (int j = 0; j < 4; j++)
            bf[j] = *(const s16x8*)&Bs[(wn + j * 16 + l16) * 32 + quad * 8];
#pragma unroll
        for (int i = 0; i < 4; i++)
#pragma unroll
            for (int j = 0; j < 4; j++)
                acc[i][j] = __builtin_amdgcn_mfma_f32_16x16x32_bf16(af[i], bf[j], acc[i][j], 0, 0, 0);
    }

#pragma unroll
    for (int j = 0; j < 4; j++) {
        const int gn = bn * 128 + wn + j * 16 + l16;
        const float bb = bias[gn];
        const int hh = gn >> 6, dd = gn & 63;
#pragma unroll
        for (int i = 0; i < 4; i++) {
            const int gm0 = bm * 128 + wm + i * 16 + quad * 4;
            const int bi = gm0 >> 11, s0 = gm0 & 2047;
            if (z == 2) {
                u32 lo = (u32)f2bf(acc[i][j][0] + bb) | ((u32)f2bf(acc[i][j][1] + bb) << 16);
                u32 hi = (u32)f2bf(acc[i][j][2] + bb) | ((u32)f2bf(acc[i][j][3] + bb) << 16);
                *(uint2*)&out[(((size_t)(bi * 8 + hh)) * 64 + dd) * 2048 + s0] = make_uint2(lo, hi);
            } else {
#pragma unroll
                for (int p = 0; p < 4; p++)
                    out[(((size_t)(bi * 8 + hh)) * 2048 + s0 + p) * 64 + dd] =
                        f2bf((acc[i][j][p] + bb) * scale);
            }
        }
    }
}

// ---------------- output projection: 128x64 tile, fp32 out ----------------
__global__ __launch_bounds__(256)
void gemm_out(const ushort_t* __restrict__ A, const ushort_t* __restrict__ W,
              const float* __restrict__ bias, float* __restrict__ out) {
    __shared__ ushort_t As[128 * 32];
    __shared__ ushort_t Bs[64 * 32];
    const int tid = threadIdx.x, bm = blockIdx.x, bn = blockIdx.y;
    const int wave = tid >> 6, lane = tid & 63, quad = lane >> 4, l16 = lane & 15;
    const ushort_t* Ag = A + (size_t)(bm * 128 + (tid >> 2)) * 512 + (tid & 3) * 8;
    const ushort_t* Bg = W + (size_t)(bn * 64 + (tid >> 2)) * 512 + (tid & 3) * 8;

    f32x4 acc[2][4];
#pragma unroll
    for (int i = 0; i < 2; i++)
#pragma unroll
        for (int j = 0; j < 4; j++) acc[i][j] = (f32x4){0.f, 0.f, 0.f, 0.f};

    for (int kt = 0; kt < 512; kt += 32) {
        __syncthreads();
        cp16(Ag + kt, (char*)As + tid * 16);
        cp16(Ag + 64 * 512 + kt, (char*)As + 4096 + tid * 16);
        cp16(Bg + kt, (char*)Bs + tid * 16);
        __syncthreads();
        s16x8 af[2], bf[4];
#pragma unroll
        for (int i = 0; i < 2; i++)
            af[i] = *(const s16x8*)&As[(wave * 32 + i * 16 + l16) * 32 + quad * 8];
#pragma unroll
        for (int j = 0; j < 4; j++)
            bf[j] = *(const s16x8*)&Bs[(j * 16 + l16) * 32 + quad * 8];
#pragma unroll
        for (int i = 0; i < 2; i++)
#pragma unroll
            for (int j = 0; j < 4; j++)
                acc[i][j] = __builtin_amdgcn_mfma_f32_16x16x32_bf16(af[i], bf[j], acc[i][j], 0, 0, 0);
    }

#pragma unroll
    for (int j = 0; j < 4; j++) {
        const int gn = bn * 64 + j * 16 + l16;
        const float bb = bias[gn];
#pragma unroll
        for (int i = 0; i < 2; i++) {
            const int gm0 = bm * 128 + wave * 32 + i * 16 + quad * 4;
#pragma unroll
            for (int p = 0; p < 4; p++)
                out[(size_t)(gm0 + p) * 512 + gn] = acc[i][j][p] + bb;
        }
    }
}

// ---------------- fused attention: 32x32 MFMA, fixed-max softmax ----------------
// grid (16 qt128, 8 h, 4 b), 256 thr. Wave owns 32 q (q = lane&31).
// S^T = K Q^T (q pre-scaled by 0.125*log2e). p = exp2(st + maskbias), no max.
// l via ones-row MFMA accumulated in C regs. P C->B frag via shfl_xor(32).
__global__ __launch_bounds__(256, 2)
void attn(const ushort_t* __restrict__ q, const ushort_t* __restrict__ k,
          const ushort_t* __restrict__ vT, const u32* __restrict__ mf,
          ushort_t* __restrict__ x) {
    __shared__ ushort_t Ks[2][64 * 64];  // double-buffered K tile, XOR chunk-swizzled

    const int tid = threadIdx.x;
    const int qt = blockIdx.x, hh = blockIdx.y, b = blockIdx.z;
    const int w = tid >> 6, L = tid & 63, hf = L >> 5, q5 = L & 31;
    const size_t bh = (size_t)b * 8 + hh;
    const ushort_t* qg = q + (bh * 2048 + qt * 128 + w * 32) * 64;
    const ushort_t* kg = k + bh * 2048 * 64;
    const ushort_t* vg = vT + bh * 64 * 2048 + (size_t)q5 * 2048;
    const u32* mg = mf + ((((size_t)b * 32) * 16 + qt) * 4 + w) * 1024 + L * 4;

    // staging source offsets (per-thread constant): lds chunk linear -> swizzled global chunk
    const int lin0 = tid, lin1 = 256 + tid;
    const int sr0 = lin0 >> 3, sc0 = lin0 & 7;
    const int sr1 = lin1 >> 3, sc1 = lin1 & 7;
    const size_t goff0 = (size_t)sr0 * 64 + (size_t)((sc0 ^ (sr0 & 7)) * 8);
    const size_t goff1 = (size_t)sr1 * 64 + (size_t)((sc1 ^ (sr1 & 7)) * 8);

    // stage K tile 0
    cp16(kg + goff0, (char*)Ks[0] + lin0 * 16);
    cp16(kg + goff1, (char*)Ks[0] + lin1 * 16);

    // Q B-frags (held whole kernel)
    s16x8 Qf[4];
#pragma unroll
    for (int s = 0; s < 4; s++)
        Qf[s] = *(const s16x8*)(qg + q5 * 64 + s * 16 + hf * 8);

    // ones A-frag (bf16 1.0 x8)
    union { u32 u[4]; s16x8 v; } ou;
    ou.u[0] = ou.u[1] = ou.u[2] = ou.u[3] = 0x3F803F80u;
    const s16x8 onesf = ou.v;

    f32x16 O0, O1, lacc;
#pragma unroll
    for (int i = 0; i < 16; i++) { O0[i] = 0.f; O1[i] = 0.f; lacc[i] = 0.f; }

    for (int it = 0; it < 32; ++it) {
        const int cur = it & 1;
        __syncthreads();  // K[cur] staged (auto vmcnt drain before barrier)
        if (it + 1 < 32) {
            const ushort_t* kn = kg + (size_t)(it + 1) * 4096;
            cp16(kn + goff0, (char*)Ks[1 - cur] + lin0 * 16);
            cp16(kn + goff1, (char*)Ks[1 - cur] + lin1 * 16);
        }

        // mask fragments (coalesced dwordx4, TA pipe)
        uint4 mj[4];
#pragma unroll
        for (int j = 0; j < 4; j++)
            mj[j] = *(const uint4*)(mg + (size_t)it * 65536 + j * 256);

        // V A-frags direct global (L1-friendly: full 128B window per row per iter)
        s16x8 Vf[2][4];
#pragma unroll
        for (int mt = 0; mt < 2; mt++)
#pragma unroll
            for (int s = 0; s < 4; s++)
                Vf[mt][s] = *(const s16x8*)(vg + (size_t)mt * 65536 + it * 64 + s * 16 + hf * 8);

        // S^T = K Q^T (32x32x16 chain over d)
        f32x16 c0, c1;
#pragma unroll
        for (int i = 0; i < 16; i++) { c0[i] = 0.f; c1[i] = 0.f; }
#pragma unroll
        for (int s = 0; s < 4; s++) {
            const s16x8 kf0 = *(const s16x8*)&Ks[cur][q5 * 64 + (((2 * s + hf) ^ (q5 & 7)) * 8)];
            c0 = __builtin_amdgcn_mfma_f32_32x32x16_bf16(kf0, Qf[s], c0, 0, 0, 0);
        }
#pragma unroll
        for (int s = 0; s < 4; s++) {
            const s16x8 kf1 = *(const s16x8*)&Ks[cur][(32 + q5) * 64 + (((2 * s + hf) ^ (q5 & 7)) * 8)];
            c1 = __builtin_amdgcn_mfma_f32_32x32x16_bf16(kf1, Qf[s], c1, 0, 0, 0);
        }

        // p = exp2(st + maskbias); pack bf16 (trunc)
        u32 P[16];
#pragma unroll
        for (int mi = 0; mi < 16; mi++) {
            const int reg = ((mi >> 1) & 3) * 4 + (mi & 1) * 2;
            const u32 mw = (mi & 3) == 0 ? mj[mi >> 2].x
                         : (mi & 3) == 1 ? mj[mi >> 2].y
                         : (mi & 3) == 2 ? mj[mi >> 2].z : mj[mi >> 2].w;
            const float b0 = __uint_as_float(mw << 16);
            const float b1 = __uint_as_float(mw & 0xffff0000u);
            const float s0 = (mi < 8) ? c0[reg] : c1[reg];
            const float s1 = (mi < 8) ? c0[reg + 1] : c1[reg + 1];
            const float e0 = __builtin_amdgcn_exp2f(s0 + b0);
            const float e1 = __builtin_amdgcn_exp2f(s1 + b1);
            P[mi] = pk_trunc(e0, e1);
        }

        // O^T += V^T P^T ; l += ones P^T   (P B-frag via shfl_xor 32 + selects)
#pragma unroll
        for (int s = 0; s < 4; s++) {
            const u32 a0 = P[4 * s], a1 = P[4 * s + 1];
            const u32 b0 = P[4 * s + 2], b1 = P[4 * s + 3];
            const u32 send0 = hf ? a0 : b0;
            const u32 send1 = hf ? a1 : b1;
            const u32 r0 = __shfl_xor((int)send0, 32);
            const u32 r1 = __shfl_xor((int)send1, 32);
            union { uint4 u; s16x8 v; } pu;
            pu.u.x = hf ? r0 : a0;
            pu.u.y = hf ? r1 : a1;
            pu.u.z = hf ? b0 : r0;
            pu.u.w = hf ? b1 : r1;
            const s16x8 Pf = pu.v;
            O0 = __builtin_amdgcn_mfma_f32_32x32x16_bf16(Vf[0][s], Pf, O0, 0, 0, 0);
            O1 = __builtin_amdgcn_mfma_f32_32x32x16_bf16(Vf[1][s], Pf, O1, 0, 0, 0);
            lacc = __builtin_amdgcn_mfma_f32_32x32x16_bf16(onesf, Pf, lacc, 0, 0, 0);
        }
    }

    const float inv = 1.0f / lacc[0];
    ushort_t* xr = x + ((size_t)b * 2048 + qt * 128 + w * 32 + q5) * 512 + hh * 64;
#pragma unroll
    for (int mt = 0; mt < 2; mt++) {
#pragma unroll
        for (int r4 = 0; r4 < 4; r4++) {
            const int d = mt * 32 + r4 * 8 + hf * 4;
            const float v0 = (mt ? O1[r4 * 4 + 0] : O0[r4 * 4 + 0]) * inv;
            const float v1 = (mt ? O1[r4 * 4 + 1] : O0[r4 * 4 + 1]) * inv;
            const float v2 = (mt ? O1[r4 * 4 + 2] : O0[r4 * 4 + 2]) * inv;
            const float v3 = (mt ? O1[r4 * 4 + 3] : O0[r4 * 4 + 3]) * inv;
            u32 lo = (u32)f2bf(v0) | ((u32)f2bf(v1) << 16);
            u32 hi = (u32)f2bf(v2) | ((u32)f2bf(v3) << 16);
            *(uint2*)(xr + d) = make_uint2(lo, hi);
        }
    }
}

// ---------------- launch ----------------
extern "C" void kernel_launch(void* const* d_in, const int* in_sizes, int n_in,
                              void* d_out, int out_size, void* d_ws, size_t ws_size,
                              hipStream_t stream) {
    const float* query = (const float*)d_in[0];
    const float* key_ = (const float*)d_in[1];
    const float* value = (const float*)d_in[2];
    const int* mask = (const int*)d_in[3];
    const float* Wq = (const float*)d_in[4];
    const float* bq = (const float*)d_in[5];
    const float* Wk = (const float*)d_in[6];
    const float* bk = (const float*)d_in[7];
    const float* Wv = (const float*)d_in[8];
    const float* bv = (const float*)d_in[9];
    const float* Wo = (const float*)d_in[10];
    const float* bo = (const float*)d_in[11];

    const size_t E = 4194304;  // 8192*512
    const size_t W = 262144;   // 512*512
    ushort_t* qb = (ushort_t*)d_ws;
    ushort_t* kb = qb + E;
    ushort_t* vb = kb + E;
    ushort_t* Wqb = vb + E;
    ushort_t* Wkb = Wqb + W;
    ushort_t* Wvb = Wkb + W;
    ushort_t* Wob = Wvb + W;
    ushort_t* mfb = Wob + W;  // 16.78M ushorts = 8.39M u32
    ushort_t* qp = mfb + (size_t)4 * 2048 * 2048;
    ushort_t* kp = qp + E;
    ushort_t* vTp = kp + E;
    ushort_t* xp = vTp + E;

    cvt_qkv<<<dim3(4096, 3), 256, 0, stream>>>(query, key_, value, qb, kb, vb);
    cvt_w<<<dim3(256, 4), 256, 0, stream>>>(Wq, Wk, Wv, Wo, Wqb, Wkb, Wvb, Wob);
    prep_mask<<<dim3(32, 16, 4), 256, 0, stream>>>(mask, (u32*)mfb);

    gemm_qkv<<<dim3(64, 4, 3), 256, 0, stream>>>(qb, kb, vb, Wqb, Wkb, Wvb,
                                                 bq, bk, bv, qp, kp, vTp);

    attn<<<dim3(16, 8, 4), 256, 0, stream>>>(qp, kp, vTp, (const u32*)mfb, xp);

    gemm_out<<<dim3(64, 8), 256, 0, stream>>>(xp, Wob, bo, (float*)d_out);
}